// Round 6
// baseline (636.522 us; speedup 1.0000x reference)
//
#include <hip/hip_runtime.h>

// AutoEncoder fused pipeline v6, bf16 MFMA (gfx950).
// 16-wave (1024-thr) blocks, 64-row x OP tiles, small wave-tiles (acc<=32 regs)
// + forced 64-reg budget -> 2 blocks x 16 waves = 32 waves/CU for latency hiding.
// Uniform bf16 glds16 staging (x pre-converted), XOR-swizzled LDS.

typedef short bf16x8 __attribute__((ext_vector_type(8)));
typedef float f32x4  __attribute__((ext_vector_type(4)));

#define B_ROWS 65536
#define EPS_LN 1e-5f

static __device__ __forceinline__ unsigned short f2bf(float f) {
    union { float f; unsigned u; } v; v.f = f;
    unsigned r = v.u + 0x7FFFu + ((v.u >> 16) & 1u);   // RNE
    return (unsigned short)(r >> 16);
}

static __device__ __forceinline__ float mish_f(float x) {
    if (x > 15.f) return x;
    float u = __expf(x);
    float p = __fmaf_rn(u, u, 2.f * u);
    return x * (p / (p + 2.f));
}

// direct global->LDS, 16B per lane; LDS base must be wave-uniform
static __device__ __forceinline__ void glds16(const void* g, void* l) {
    typedef __attribute__((address_space(3))) unsigned lds_u32;
    typedef __attribute__((address_space(1))) const unsigned glb_u32;
    lds_u32* lp = (lds_u32*)l;
    unsigned lofs = __builtin_amdgcn_readfirstlane((unsigned)(unsigned long long)lp);
    lp = (lds_u32*)(unsigned long long)lofs;
    __builtin_amdgcn_global_load_lds((glb_u32*)g, lp, 16, 0, 0);
}

// ---------------- x fp32 -> bf16 streaming conversion ----------------
__global__ __launch_bounds__(256)
void cvtx_kernel(const float* __restrict__ x, unsigned short* __restrict__ xb) {
    size_t i = ((size_t)blockIdx.x * 256 + threadIdx.x) * 8;
    float4 a = *(const float4*)(x + i);
    float4 b = *(const float4*)(x + i + 4);
    union { unsigned short us[8]; uint4 v; } u;
    u.us[0] = f2bf(a.x); u.us[1] = f2bf(a.y); u.us[2] = f2bf(a.z); u.us[3] = f2bf(a.w);
    u.us[4] = f2bf(b.x); u.us[5] = f2bf(b.y); u.us[6] = f2bf(b.z); u.us[7] = f2bf(b.w);
    *(uint4*)(xb + i) = u.v;
}

// ---------------- padded weight fp32->bf16 conversion ----------------
struct CvtArgs {
    const float* src[6];
    unsigned short* dst[6];
    int O[6], K[6], KP[6];
    int base[7];
};

__global__ void wpad_kernel(CvtArgs a) {
    int b = blockIdx.x;
    int seg = 0;
    while (b >= a.base[seg + 1]) ++seg;
    int r = b - a.base[seg];
    int O = a.O[seg], K = a.K[seg], KP = a.KP[seg];
    const float* s = a.src[seg];
    unsigned short* d = a.dst[seg];
    for (int c = threadIdx.x; c < KP; c += 256) {
        unsigned short v = 0;
        if (r < O && c < K) v = f2bf(s[(size_t)r * K + c]);
        d[(size_t)r * KP + c] = v;
    }
}

// ---------------- fused layer kernel ----------------
// Block: 1024 threads = 16 waves, WR(row-groups) x WC(col-groups).
// Tile: 64 rows x OP cols; wave-tile (64/WR) x (OP/WC); BK=32.
// Double-buffered LDS, one __syncthreads per K-step. acc <= 32 regs/wave;
// __launch_bounds__(1024,8) forces <=64 regs -> 2 blocks/CU (32 waves).
template<int KP, int ASTR, int OP, int OREAL, int OSTRIDE, int NKT,
         int WR, bool HASBIAS, bool ABS, bool LN>
__global__ __launch_bounds__(1024, 8)
void layer6(const unsigned short* __restrict__ Asrc,
            const unsigned short* __restrict__ Wp,
            const float* __restrict__ gam,
            const float* __restrict__ bet,
            const float* __restrict__ bias,
            void* __restrict__ Aout,
            float* __restrict__ partials,
            int cbase)
{
    constexpr int WC    = 16 / WR;
    constexpr int NT    = OP / (WC * 16);      // col frags per wave
    constexpr int AR    = 4 / WR;              // row frags per wave
    constexpr int WROWS = 16 * AR;
    constexpr int NCH_W = OP / 16;             // 1KB W chunks per K-step
    constexpr int NCH   = NCH_W + 4;           // + 4 A chunks
    constexpr int MAXC  = (NCH + 15) / 16;
    constexpr int ABY   = 4096;                // 64 x 32 bf16
    constexpr int WBY   = OP * 64;

    __shared__ __align__(16) char smem[2 * ABY + 2 * WBY];

    const int tid  = threadIdx.x;
    const int lane = tid & 63;
    const int wu   = __builtin_amdgcn_readfirstlane(tid >> 6);  // scalar wave id
    const int wrI = wu / WC, wcI = wu % WC;
    const int lg = lane >> 4, lc = lane & 15;
    const int row0 = blockIdx.x * 64;

    // per-lane swizzled voffsets (shared by all chunks of same stride)
    const size_t vofW = (size_t)(((lane >> 2) * KP   + (((lane & 3) ^ ((lane >> 3) & 3)) << 3)) * 2);
    const size_t vofA = (size_t)(((lane >> 2) * ASTR + (((lane & 3) ^ ((lane >> 3) & 3)) << 3)) * 2);

    auto stage = [&](int t, int b) {
#pragma unroll
        for (int i = 0; i < MAXC; ++i) {
            int c = wu + 16 * i;              // scalar
            if (c < NCH) {
                if (c < NCH_W) {
                    const char* g = (const char*)Wp +
                        ((size_t)(cbase + c * 16) * KP) * 2 + (size_t)t * 64 + vofW;
                    glds16(g, smem + (2 * ABY + b * WBY + c * 1024));
                } else {
                    int ca = c - NCH_W;
                    const char* g = (const char*)Asrc +
                        ((size_t)(row0 + ca * 16) * ASTR) * 2 + (size_t)t * 64 + vofA;
                    glds16(g, smem + (b * ABY + ca * 1024));
                }
            }
        }
    };

    // ---- prologue ----
    stage(0, 0);
    __syncthreads();

    // ---- main K loop ----
    f32x4 acc[AR][NT];
#pragma unroll
    for (int a = 0; a < AR; ++a)
#pragma unroll
        for (int c = 0; c < NT; ++c) acc[a][c] = (f32x4){0.f, 0.f, 0.f, 0.f};

    const int fswz = ((lg ^ ((lc >> 1) & 3)) << 4);

    for (int t = 0; t < NKT; ++t) {
        const int bsel = t & 1;
        if (t + 1 < NKT) stage(t + 1, bsel ^ 1);

        const char* Ab = smem + bsel * ABY + (wrI * WROWS + lc) * 64 + fswz;
        const char* Bb = smem + 2 * ABY + bsel * WBY + (wcI * NT * 16 + lc) * 64 + fswz;
        bf16x8 afr[AR], bfr[NT];
#pragma unroll
        for (int a = 0; a < AR; ++a) afr[a] = *(const bf16x8*)(Ab + a * 1024);
#pragma unroll
        for (int c = 0; c < NT; ++c) bfr[c] = *(const bf16x8*)(Bb + c * 1024);

#pragma unroll
        for (int c = 0; c < NT; ++c)
#pragma unroll
            for (int a = 0; a < AR; ++a)
                acc[a][c] = __builtin_amdgcn_mfma_f32_16x16x32_bf16(afr[a], bfr[c], acc[a][c], 0, 0, 0);
        __syncthreads();
    }

    // ---- epilogue ----
    if constexpr (LN) {
        if constexpr (HASBIAS) {
#pragma unroll
            for (int c = 0; c < NT; ++c) {
                int col = wcI * NT * 16 + c * 16 + lc;
                float bv = (col < OREAL) ? bias[col] : 0.f;
#pragma unroll
                for (int a = 0; a < AR; ++a)
#pragma unroll
                    for (int r = 0; r < 4; ++r) acc[a][c][r] += bv;
            }
        }
        float ps1[AR][4], ps2[AR][4];
#pragma unroll
        for (int a = 0; a < AR; ++a)
#pragma unroll
            for (int r = 0; r < 4; ++r) { ps1[a][r] = 0.f; ps2[a][r] = 0.f; }
#pragma unroll
        for (int a = 0; a < AR; ++a)
#pragma unroll
            for (int c = 0; c < NT; ++c)
#pragma unroll
                for (int r = 0; r < 4; ++r) {
                    float v = acc[a][c][r];
                    ps1[a][r] += v;
                    ps2[a][r] = __fmaf_rn(v, v, ps2[a][r]);
                }
#pragma unroll
        for (int m = 1; m < 16; m <<= 1)
#pragma unroll
            for (int a = 0; a < AR; ++a)
#pragma unroll
                for (int r = 0; r < 4; ++r) {
                    ps1[a][r] += __shfl_xor(ps1[a][r], m);
                    ps2[a][r] += __shfl_xor(ps2[a][r], m);
                }

        float* lnP   = (float*)smem;                 // [64][WC] s1, s2 at +64*WC
        float* lnMR  = (float*)(smem + 8192);        // [128]
        float* wsumP = (float*)(smem + 8192 + 512);  // [16]

        if (lc == 0) {
#pragma unroll
            for (int a = 0; a < AR; ++a)
#pragma unroll
                for (int r = 0; r < 4; ++r) {
                    int rl = wrI * WROWS + a * 16 + lg * 4 + r;
                    lnP[rl * WC + wcI]           = ps1[a][r];
                    lnP[64 * WC + rl * WC + wcI] = ps2[a][r];
                }
        }
        __syncthreads();
        if (tid < 64) {
            float s1 = 0.f, s2 = 0.f;
#pragma unroll
            for (int w = 0; w < WC; ++w) {
                s1 += lnP[tid * WC + w];
                s2 += lnP[64 * WC + tid * WC + w];
            }
            float mu = s1 * (1.f / OREAL);
            float var = fmaxf(s2 * (1.f / OREAL) - mu * mu, 0.f);
            lnMR[tid]      = mu;
            lnMR[64 + tid] = rsqrtf(var + EPS_LN);
        }
        __syncthreads();

        float gcol[NT], bcol[NT];
#pragma unroll
        for (int c = 0; c < NT; ++c) {
            int col = wcI * NT * 16 + c * 16 + lc;
            gcol[c] = (col < OREAL) ? gam[col] : 0.f;
            bcol[c] = (col < OREAL) ? bet[col] : 0.f;
        }

        float asum = 0.f;
        unsigned short* outp = (unsigned short*)Aout;
#pragma unroll
        for (int a = 0; a < AR; ++a)
#pragma unroll
            for (int r = 0; r < 4; ++r) {
                int rl = wrI * WROWS + a * 16 + lg * 4 + r;
                float mu = lnMR[rl], rs = lnMR[64 + rl];
                size_t rowoff = (size_t)(row0 + rl) * OSTRIDE;
#pragma unroll
                for (int c = 0; c < NT; ++c) {
                    int col = wcI * NT * 16 + c * 16 + lc;
                    if (col < OSTRIDE) {
                        unsigned short outv = 0;
                        if (col < OREAL) {
                            float v = (acc[a][c][r] - mu) * rs * gcol[c] + bcol[c];
                            float mz = mish_f(v);
                            if (ABS) asum += fabsf(mz);
                            outv = f2bf(mz);
                        }
                        outp[rowoff + col] = outv;
                    }
                }
            }

        if constexpr (ABS) {
#pragma unroll
            for (int m = 1; m < 64; m <<= 1) asum += __shfl_xor(asum, m);
            if (lane == 0) wsumP[tid >> 6] = asum;
            __syncthreads();
            if (tid == 0) {
                float s = 0.f;
                for (int w = 0; w < 16; ++w) s += wsumP[w];
                partials[blockIdx.x] = s;
            }
        }
    } else {
        // final layer: bias + sigmoid, fp32 out
        float* outp = (float*)Aout;
#pragma unroll
        for (int c = 0; c < NT; ++c) {
            int col = cbase + wcI * NT * 16 + c * 16 + lc;
            bool ok = col < OREAL;
            float bv = ok ? bias[col] : 0.f;
#pragma unroll
            for (int a = 0; a < AR; ++a)
#pragma unroll
                for (int r = 0; r < 4; ++r) {
                    if (ok) {
                        int rl = wrI * WROWS + a * 16 + lg * 4 + r;
                        float v = acc[a][c][r] + bv;
                        outp[(size_t)(row0 + rl) * OSTRIDE + col] = 1.f / (1.f + __expf(-v));
                    }
                }
        }
    }
}

// ---------------- deterministic reduction of |latent| partials ----------------
__global__ void reduce_abs(const float* __restrict__ partials, float* __restrict__ out) {
    __shared__ float sm[256];
    float s = 0.f;
    for (int i = threadIdx.x; i < 1024; i += 256) s += partials[i];  // fixed order
    sm[threadIdx.x] = s;
    __syncthreads();
    for (int step = 128; step > 0; step >>= 1) {
        if (threadIdx.x < step) sm[threadIdx.x] += sm[threadIdx.x + step];
        __syncthreads();
    }
    if (threadIdx.x == 0) out[0] = sm[0];
}

extern "C" void kernel_launch(void* const* d_in, const int* in_sizes, int n_in,
                              void* d_out, int out_size, void* d_ws, size_t ws_size,
                              hipStream_t stream)
{
    const float* x   = (const float*)d_in[0];
    const float* W1  = (const float*)d_in[1];
    const float* g1  = (const float*)d_in[2];
    const float* b1  = (const float*)d_in[3];
    const float* W2  = (const float*)d_in[4];
    const float* g2  = (const float*)d_in[5];
    const float* b2  = (const float*)d_in[6];
    const float* W3  = (const float*)d_in[7];
    const float* b3  = (const float*)d_in[8];
    const float* gh  = (const float*)d_in[9];
    const float* bh  = (const float*)d_in[10];
    const float* D1  = (const float*)d_in[11];
    const float* g3  = (const float*)d_in[12];
    const float* b3n = (const float*)d_in[13];
    const float* D2  = (const float*)d_in[14];
    const float* g4  = (const float*)d_in[15];
    const float* b4  = (const float*)d_in[16];
    const float* D3  = (const float*)d_in[17];
    const float* bo  = (const float*)d_in[18];

    char* ws = (char*)d_ws;
    size_t off = 0;
    auto alloc = [&](size_t bytes) -> char* {
        char* p = ws + off;
        off += (bytes + 255) & ~(size_t)255;
        return p;
    };
    unsigned short* W1p = (unsigned short*)alloc((size_t)512 * 800 * 2);
    unsigned short* W2p = (unsigned short*)alloc((size_t)384 * 512 * 2);
    unsigned short* W3p = (unsigned short*)alloc((size_t)128 * 288 * 2);
    unsigned short* D1p = (unsigned short*)alloc((size_t)384 * 128 * 2);
    unsigned short* D2p = (unsigned short*)alloc((size_t)512 * 288 * 2);
    unsigned short* D3p = (unsigned short*)alloc((size_t)896 * 512 * 2);
    unsigned short* xbf = (unsigned short*)alloc((size_t)B_ROWS * 784 * 2 + 256);
    unsigned short* actP = (unsigned short*)alloc((size_t)B_ROWS * 512 * 2 + 256);
    unsigned short* actQ = (unsigned short*)alloc((size_t)B_ROWS * 288 * 2 + 256);
    unsigned short* actL = (unsigned short*)alloc((size_t)B_ROWS * 128 * 2 + 256);
    float* partials = (float*)alloc(1024 * 4);

    // x -> bf16 (65536*784 = 25088 * 2048 elems)
    cvtx_kernel<<<25088, 256, 0, stream>>>(x, xbf);

    CvtArgs ca;
    ca.src[0] = W1; ca.dst[0] = W1p; ca.O[0] = 512; ca.K[0] = 784; ca.KP[0] = 800;
    ca.src[1] = W2; ca.dst[1] = W2p; ca.O[1] = 264; ca.K[1] = 512; ca.KP[1] = 512;
    ca.src[2] = W3; ca.dst[2] = W3p; ca.O[2] = 128; ca.K[2] = 264; ca.KP[2] = 288;
    ca.src[3] = D1; ca.dst[3] = D1p; ca.O[3] = 264; ca.K[3] = 128; ca.KP[3] = 128;
    ca.src[4] = D2; ca.dst[4] = D2p; ca.O[4] = 512; ca.K[4] = 264; ca.KP[4] = 288;
    ca.src[5] = D3; ca.dst[5] = D3p; ca.O[5] = 784; ca.K[5] = 512; ca.KP[5] = 512;
    ca.base[0] = 0;    ca.base[1] = 512;  ca.base[2] = 896;
    ca.base[3] = 1024; ca.base[4] = 1408; ca.base[5] = 1920; ca.base[6] = 2816;
    wpad_kernel<<<2816, 256, 0, stream>>>(ca);

    const int NB = B_ROWS / 64;  // 1024 row-tiles

    // L1: xbf[.,784] @ W1^T -> 512, LN, mish   (WR1: wave 64x32)
    layer6<800, 784, 512, 512, 512, 25, 1, false, false, true>
        <<<NB, 1024, 0, stream>>>(xbf, W1p, g1, b1, nullptr, actP, nullptr, 0);
    // L2: 512 -> 264 (OP 384), LN, mish, stride 288   (WR2: wave 32x48)
    layer6<512, 512, 384, 264, 288, 16, 2, false, false, true>
        <<<NB, 1024, 0, stream>>>(actP, W2p, g2, b2, nullptr, actQ, nullptr, 0);
    // L3: 288 -> 128, +b3, LN, mish, abs-partials   (WR2: wave 32x16)
    layer6<288, 288, 128, 128, 128, 9, 2, true, true, true>
        <<<NB, 1024, 0, stream>>>(actQ, W3p, gh, bh, b3, actL, partials, 0);
    // L4: 128 -> 264 (OP 384), LN, mish, stride 288
    layer6<128, 128, 384, 264, 288, 4, 2, false, false, true>
        <<<NB, 1024, 0, stream>>>(actL, D1p, g3, b3n, nullptr, actQ, nullptr, 0);
    // L5: 288 -> 512, LN, mish
    layer6<288, 288, 512, 512, 512, 9, 1, false, false, true>
        <<<NB, 1024, 0, stream>>>(actQ, D2p, g4, b4, nullptr, actP, nullptr, 0);
    // L6: 512 -> 784, +bo, sigmoid, fp32 out (cols 0-511, then 512-783)
    layer6<512, 512, 512, 784, 784, 16, 1, true, false, false>
        <<<NB, 1024, 0, stream>>>(actP, D3p, nullptr, nullptr, bo, d_out, nullptr, 0);
    layer6<512, 512, 384, 784, 784, 16, 2, true, false, false>
        <<<NB, 1024, 0, stream>>>(actP, D3p, nullptr, nullptr, bo, d_out, nullptr, 512);

    reduce_abs<<<1, 256, 0, stream>>>(partials, (float*)d_out + (size_t)B_ROWS * 784);
}

// Round 7
// 540.090 us; speedup vs baseline: 1.1785x; 1.1785x over previous
//
#include <hip/hip_runtime.h>

// AutoEncoder v7: whole-network mega-fusion, bf16 MFMA (gfx950).
// One 1024-thread block (16 waves, 2x8) processes 64 rows through ALL 6
// layers; inter-layer activations live in LDS (h-tiles, XOR-swizzled);
// weights stream from L2 via global_load_lds per phase. No HBM round-trips
// between layers.
//
// LDS plan (byte offsets, 151552 total):
//  P1(L1): h1@0-64K   A-dbuf@64K-72K  Wst@72K-139K(2x32K)  scratch@72K(post)
//  P2(L2): A=h1@0     h2@64K-100K     Wst@100K-148K(2x24K) scratch@100K
//  P3(L3): A=h2@64K   h3@0-16K        Wst@100K-116K(2x8K)  scratch@100K
//  P4(L4): A=h3@0     h4@64K-100K     Wst@16K-64K(2x24K)   scratch@16K
//  P5(L5): A=h4@64K   h5@0-64K        Wst@100K-132K(1x32K) scratch@100K
//  P6(L6): A=h5@0     out->global     Wst@64K-128K(2x32K)  [two col passes]

typedef short bf16x8 __attribute__((ext_vector_type(8)));
typedef float f32x4  __attribute__((ext_vector_type(4)));

#define B_ROWS 65536
#define EPS_LN 1e-5f

static __device__ __forceinline__ unsigned short f2bf(float f) {
    union { float f; unsigned u; } v; v.f = f;
    unsigned r = v.u + 0x7FFFu + ((v.u >> 16) & 1u);   // RNE
    return (unsigned short)(r >> 16);
}

static __device__ __forceinline__ float mish_f(float x) {
    if (x > 15.f) return x;
    float u = __expf(x);
    float p = __fmaf_rn(u, u, 2.f * u);
    return x * (p / (p + 2.f));
}

// direct global->LDS, 16B per lane; LDS base must be wave-uniform
static __device__ __forceinline__ void glds16(const void* g, void* l) {
    typedef __attribute__((address_space(3))) unsigned lds_u32;
    typedef __attribute__((address_space(1))) const unsigned glb_u32;
    lds_u32* lp = (lds_u32*)l;
    unsigned lofs = __builtin_amdgcn_readfirstlane((unsigned)(unsigned long long)lp);
    lp = (lds_u32*)(unsigned long long)lofs;
    __builtin_amdgcn_global_load_lds((glb_u32*)g, lp, 16, 0, 0);
}

// ---------------- padded weight fp32->bf16 conversion ----------------
struct CvtArgs {
    const float* src[6];
    unsigned short* dst[6];
    int O[6], K[6], KP[6];
    int base[7];
};

__global__ void wpad_kernel(CvtArgs a) {
    int b = blockIdx.x;
    int seg = 0;
    while (b >= a.base[seg + 1]) ++seg;
    int r = b - a.base[seg];
    int O = a.O[seg], K = a.K[seg], KP = a.KP[seg];
    const float* s = a.src[seg];
    unsigned short* d = a.dst[seg];
    for (int c = threadIdx.x; c < KP; c += 256) {
        unsigned short v = 0;
        if (r < O && c < K) v = f2bf(s[(size_t)r * K + c]);
        d[(size_t)r * KP + c] = v;
    }
}

// ---------------- generic GEMM phase over LDS-resident A ----------------
// 16 waves (2 row x 8 col), tile 64 x OP, BK=32. A read from h-tile
// (row-major, 64B k-chunks, 16B-slot XOR swizzle by (row>>1)&3).
template<int NKT, int OP, int KP, int WSTB, bool WDB, int ABASE, int ASTRLDS>
__device__ __forceinline__ void gemm_h(char* smem,
    const unsigned short* __restrict__ Wp, int cbase,
    int lane, int wu, int wrI, int wcI, int lg, int lc, int fswz,
    f32x4 (&acc)[2][OP / 128])
{
    constexpr int NT = OP / 128, NCHW = OP / 16, MAXC = (NCHW + 15) / 16;
    constexpr int WBY = OP * 64;
    const size_t vofW = ((size_t)(lane >> 2) * KP +
                         (size_t)((((lane & 3) ^ ((lane >> 3) & 3))) << 3)) * 2;
    auto stage = [&](int t, int b) {
#pragma unroll
        for (int i = 0; i < MAXC; ++i) {
            int c = wu + 16 * i;
            if (c < NCHW) {
                const char* g = (const char*)Wp +
                    ((size_t)(cbase + c * 16) * KP) * 2 + (size_t)t * 64 + vofW;
                glds16(g, smem + WSTB + (WDB ? b * WBY : 0) + c * 1024);
            }
        }
    };
    if constexpr (WDB) stage(0, 0);
    __syncthreads();
    for (int t = 0; t < NKT; ++t) {
        int bsel = 0;
        if constexpr (WDB) {
            bsel = t & 1;
            if (t + 1 < NKT) stage(t + 1, bsel ^ 1);
        } else {
            stage(t, 0);
            __syncthreads();
        }
        bf16x8 afr[2], bfr[NT];
#pragma unroll
        for (int a = 0; a < 2; ++a) {
            int arow = wrI * 32 + a * 16 + lc;
            afr[a] = *(const bf16x8*)(smem + ABASE + arow * ASTRLDS + t * 64 + fswz);
        }
#pragma unroll
        for (int c = 0; c < NT; ++c) {
            int wrow = wcI * (NT * 16) + c * 16 + lc;
            bfr[c] = *(const bf16x8*)(smem + WSTB + (WDB ? bsel * WBY : 0) + wrow * 64 + fswz);
        }
#pragma unroll
        for (int c = 0; c < NT; ++c)
#pragma unroll
            for (int a = 0; a < 2; ++a)
                acc[a][c] = __builtin_amdgcn_mfma_f32_16x16x32_bf16(afr[a], bfr[c], acc[a][c], 0, 0, 0);
        __syncthreads();
    }
}

// ---------------- P1 GEMM: fp32 x with inline cvt, A double-buffered ----------------
template<int NKT, int OP, int KP, int WSTB, int ABASE>
__device__ __forceinline__ void gemm_f32(char* smem,
    const unsigned short* __restrict__ Wp, const float* __restrict__ x, int row0,
    int tid, int lane, int wu, int wrI, int wcI, int lg, int lc, int fswz,
    f32x4 (&acc)[2][OP / 128])
{
    constexpr int NT = OP / 128, NCHW = OP / 16, MAXC = (NCHW + 15) / 16;
    constexpr int WBY = OP * 64;
    const size_t vofW = ((size_t)(lane >> 2) * KP +
                         (size_t)((((lane & 3) ^ ((lane >> 3) & 3))) << 3)) * 2;
    auto stage = [&](int t, int b) {
#pragma unroll
        for (int i = 0; i < MAXC; ++i) {
            int c = wu + 16 * i;
            if (c < NCHW) {
                const char* g = (const char*)Wp +
                    ((size_t)c * 16 * KP) * 2 + (size_t)t * 64 + vofW;
                glds16(g, smem + WSTB + b * WBY + c * 1024);
            }
        }
    };
    const int ar = tid >> 2, as = tid & 3;
    const float* axp = x + (size_t)(row0 + ar) * 784 + as * 8;
    const int aswz = ar * 64 + ((as ^ ((ar >> 1) & 3)) << 4);
    float4 rA0 = make_float4(0, 0, 0, 0), rA1 = make_float4(0, 0, 0, 0);
    auto loadA1 = [&](int t) {
        int c0 = t * 32 + as * 8;
        rA0 = (c0     < 784) ? *(const float4*)(axp + t * 32)     : make_float4(0, 0, 0, 0);
        rA1 = (c0 + 4 < 784) ? *(const float4*)(axp + t * 32 + 4) : make_float4(0, 0, 0, 0);
    };
    auto pubA = [&](int b) {
        union { unsigned short us[8]; uint4 v; } u;
        u.us[0] = f2bf(rA0.x); u.us[1] = f2bf(rA0.y);
        u.us[2] = f2bf(rA0.z); u.us[3] = f2bf(rA0.w);
        u.us[4] = f2bf(rA1.x); u.us[5] = f2bf(rA1.y);
        u.us[6] = f2bf(rA1.z); u.us[7] = f2bf(rA1.w);
        *(uint4*)(smem + ABASE + b * 4096 + aswz) = u.v;
    };
    stage(0, 0);
    if (tid < 256) { loadA1(0); pubA(0); if (NKT > 1) loadA1(1); }
    __syncthreads();
    for (int t = 0; t < NKT; ++t) {
        const int bsel = t & 1;
        if (t + 1 < NKT) stage(t + 1, bsel ^ 1);
        bf16x8 afr[2], bfr[NT];
#pragma unroll
        for (int a = 0; a < 2; ++a) {
            int arow = wrI * 32 + a * 16 + lc;
            afr[a] = *(const bf16x8*)(smem + ABASE + bsel * 4096 + arow * 64 + fswz);
        }
#pragma unroll
        for (int c = 0; c < NT; ++c) {
            int wrow = wcI * (NT * 16) + c * 16 + lc;
            bfr[c] = *(const bf16x8*)(smem + WSTB + bsel * WBY + wrow * 64 + fswz);
        }
        if (tid < 256) {
            if (t + 1 < NKT) pubA(bsel ^ 1);
            if (t + 2 < NKT) loadA1(t + 2);
        }
#pragma unroll
        for (int c = 0; c < NT; ++c)
#pragma unroll
            for (int a = 0; a < 2; ++a)
                acc[a][c] = __builtin_amdgcn_mfma_f32_16x16x32_bf16(afr[a], bfr[c], acc[a][c], 0, 0, 0);
        __syncthreads();
    }
}

// ---------------- LN + mish epilogue, writes swizzled h-tile ----------------
template<int OP, int OREAL, int OSTR, int HBASE, int HSTR, int SCR, bool HB, bool ABS>
__device__ __forceinline__ void ln_epi(char* smem, f32x4 (&acc)[2][OP / 128],
    const float* __restrict__ gam, const float* __restrict__ bet,
    const float* __restrict__ bias, float* __restrict__ partials,
    int tid, int lane, int wu, int wrI, int wcI, int lg, int lc, int bidx)
{
    constexpr int NT = OP / 128;
    if constexpr (HB) {
#pragma unroll
        for (int c = 0; c < NT; ++c) {
            int col = wcI * (NT * 16) + c * 16 + lc;
            float bv = (col < OREAL) ? bias[col] : 0.f;
#pragma unroll
            for (int a = 0; a < 2; ++a)
#pragma unroll
                for (int r = 0; r < 4; ++r) acc[a][c][r] += bv;
        }
    }
    float ps1[2][4], ps2[2][4];
#pragma unroll
    for (int a = 0; a < 2; ++a)
#pragma unroll
        for (int r = 0; r < 4; ++r) { ps1[a][r] = 0.f; ps2[a][r] = 0.f; }
#pragma unroll
    for (int a = 0; a < 2; ++a)
#pragma unroll
        for (int c = 0; c < NT; ++c)
#pragma unroll
            for (int r = 0; r < 4; ++r) {
                float v = acc[a][c][r];
                ps1[a][r] += v;
                ps2[a][r] = __fmaf_rn(v, v, ps2[a][r]);
            }
#pragma unroll
    for (int m = 1; m < 16; m <<= 1)
#pragma unroll
        for (int a = 0; a < 2; ++a)
#pragma unroll
            for (int r = 0; r < 4; ++r) {
                ps1[a][r] += __shfl_xor(ps1[a][r], m);
                ps2[a][r] += __shfl_xor(ps2[a][r], m);
            }
    float* lnP  = (float*)(smem + SCR);          // [64][8] s1 | [64][8] s2
    float* lnMR = (float*)(smem + SCR + 4096);   // [128]
    float* wsum = (float*)(smem + SCR + 4608);   // [16]
    if (lc == 0) {
#pragma unroll
        for (int a = 0; a < 2; ++a)
#pragma unroll
            for (int r = 0; r < 4; ++r) {
                int row = wrI * 32 + a * 16 + lg * 4 + r;
                lnP[row * 8 + wcI]       = ps1[a][r];
                lnP[512 + row * 8 + wcI] = ps2[a][r];
            }
    }
    __syncthreads();
    if (tid < 64) {
        float s1 = 0.f, s2 = 0.f;
#pragma unroll
        for (int w = 0; w < 8; ++w) { s1 += lnP[tid * 8 + w]; s2 += lnP[512 + tid * 8 + w]; }
        float mu = s1 * (1.f / OREAL);
        float var = fmaxf(s2 * (1.f / OREAL) - mu * mu, 0.f);
        lnMR[tid]      = mu;
        lnMR[64 + tid] = rsqrtf(var + EPS_LN);
    }
    __syncthreads();
    float gcol[NT], bcol[NT];
#pragma unroll
    for (int c = 0; c < NT; ++c) {
        int col = wcI * (NT * 16) + c * 16 + lc;
        gcol[c] = (col < OREAL) ? gam[col] : 0.f;
        bcol[c] = (col < OREAL) ? bet[col] : 0.f;
    }
    float asum = 0.f;
#pragma unroll
    for (int a = 0; a < 2; ++a)
#pragma unroll
        for (int r = 0; r < 4; ++r) {
            int rowl = wrI * 32 + a * 16 + lg * 4 + r;
            float mu = lnMR[rowl], rs = lnMR[64 + rowl];
            int sx = (rowl >> 1) & 3;
            int rowb = HBASE + rowl * HSTR;
#pragma unroll
            for (int c = 0; c < NT; ++c) {
                int col = wcI * (NT * 16) + c * 16 + lc;
                if (col < OSTR) {
                    unsigned short outv = 0;
                    if (col < OREAL) {
                        float v = (acc[a][c][r] - mu) * rs * gcol[c] + bcol[c];
                        float mz = mish_f(v);
                        if (ABS) asum += fabsf(mz);
                        outv = f2bf(mz);
                    }
                    int byte = rowb + ((col >> 5) << 6) +
                               ((((col >> 3) & 3) ^ sx) << 4) + ((col & 7) << 1);
                    *(unsigned short*)(smem + byte) = outv;
                }
            }
        }
    if constexpr (ABS) {
#pragma unroll
        for (int m = 1; m < 64; m <<= 1) asum += __shfl_xor(asum, m);
        if (lane == 0) wsum[wu] = asum;
        __syncthreads();
        if (tid == 0) {
            float s = 0.f;
            for (int w = 0; w < 16; ++w) s += wsum[w];
            partials[bidx] = s;
        }
    }
    __syncthreads();
}

// ---------------- final-layer epilogue: bias + sigmoid -> global fp32 ----------------
template<int OP, int CB>
__device__ __forceinline__ void out_epi(f32x4 (&acc)[2][OP / 128],
    const float* __restrict__ bo, float* __restrict__ outp, int row0,
    int wrI, int wcI, int lg, int lc)
{
    constexpr int NT = OP / 128;
#pragma unroll
    for (int c = 0; c < NT; ++c) {
        int col = CB + wcI * (NT * 16) + c * 16 + lc;
        bool ok = col < 784;
        float bv = ok ? bo[col] : 0.f;
#pragma unroll
        for (int a = 0; a < 2; ++a)
#pragma unroll
            for (int r = 0; r < 4; ++r) {
                if (ok) {
                    int rowl = wrI * 32 + a * 16 + lg * 4 + r;
                    float v = acc[a][c][r] + bv;
                    outp[(size_t)(row0 + rowl) * 784 + col] = 1.f / (1.f + __expf(-v));
                }
            }
    }
    __syncthreads();
}

// ---------------- mega kernel ----------------
struct NetArgs {
    const float* x;
    const unsigned short *W1, *W2, *W3, *D1, *D2, *D3;
    const float *g1, *b1, *g2, *b2, *gh, *bh, *b3, *g3, *b3n, *g4, *b4, *bo;
    float* out;
    float* partials;
};

__global__ __launch_bounds__(1024)
void meganet(NetArgs A)
{
    __shared__ __align__(16) char smem[151552];
    const int tid  = threadIdx.x;
    const int lane = tid & 63;
    const int wu   = __builtin_amdgcn_readfirstlane(tid >> 6);
    const int wrI = wu >> 3, wcI = wu & 7;
    const int lg = lane >> 4, lc = lane & 15;
    const int fswz = ((lg ^ ((lc >> 1) & 3)) << 4);
    const int row0 = blockIdx.x * 64;
    const int bidx = blockIdx.x;

    // P1: x(784) -> h1(512), LN(g1,b1), mish
    {
        f32x4 acc[2][4];
#pragma unroll
        for (int a = 0; a < 2; ++a)
#pragma unroll
            for (int c = 0; c < 4; ++c) acc[a][c] = (f32x4){0.f, 0.f, 0.f, 0.f};
        gemm_f32<25, 512, 800, 73728, 65536>(smem, A.W1, A.x, row0,
            tid, lane, wu, wrI, wcI, lg, lc, fswz, acc);
        ln_epi<512, 512, 512, 0, 1024, 73728, false, false>(smem, acc,
            A.g1, A.b1, nullptr, nullptr, tid, lane, wu, wrI, wcI, lg, lc, bidx);
    }
    // P2: h1(512) -> h2(264/288), LN(g2,b2), mish
    {
        f32x4 acc[2][3];
#pragma unroll
        for (int a = 0; a < 2; ++a)
#pragma unroll
            for (int c = 0; c < 3; ++c) acc[a][c] = (f32x4){0.f, 0.f, 0.f, 0.f};
        gemm_h<16, 384, 512, 102400, true, 0, 1024>(smem, A.W2, 0,
            lane, wu, wrI, wcI, lg, lc, fswz, acc);
        ln_epi<384, 264, 288, 65536, 576, 102400, false, false>(smem, acc,
            A.g2, A.b2, nullptr, nullptr, tid, lane, wu, wrI, wcI, lg, lc, bidx);
    }
    // P3: h2(288) -> h3(128), +b3, LN(gh,bh), mish, abs partials
    {
        f32x4 acc[2][1];
#pragma unroll
        for (int a = 0; a < 2; ++a) acc[a][0] = (f32x4){0.f, 0.f, 0.f, 0.f};
        gemm_h<9, 128, 288, 102400, true, 65536, 576>(smem, A.W3, 0,
            lane, wu, wrI, wcI, lg, lc, fswz, acc);
        ln_epi<128, 128, 128, 0, 256, 102400, true, true>(smem, acc,
            A.gh, A.bh, A.b3, A.partials, tid, lane, wu, wrI, wcI, lg, lc, bidx);
    }
    // P4: h3(128) -> h4(264/288), LN(g3,b3n), mish
    {
        f32x4 acc[2][3];
#pragma unroll
        for (int a = 0; a < 2; ++a)
#pragma unroll
            for (int c = 0; c < 3; ++c) acc[a][c] = (f32x4){0.f, 0.f, 0.f, 0.f};
        gemm_h<4, 384, 128, 16384, true, 0, 256>(smem, A.D1, 0,
            lane, wu, wrI, wcI, lg, lc, fswz, acc);
        ln_epi<384, 264, 288, 65536, 576, 16384, false, false>(smem, acc,
            A.g3, A.b3n, nullptr, nullptr, tid, lane, wu, wrI, wcI, lg, lc, bidx);
    }
    // P5: h4(288) -> h5(512), LN(g4,b4), mish  (single-buffered W)
    {
        f32x4 acc[2][4];
#pragma unroll
        for (int a = 0; a < 2; ++a)
#pragma unroll
            for (int c = 0; c < 4; ++c) acc[a][c] = (f32x4){0.f, 0.f, 0.f, 0.f};
        gemm_h<9, 512, 288, 102400, false, 65536, 576>(smem, A.D2, 0,
            lane, wu, wrI, wcI, lg, lc, fswz, acc);
        ln_epi<512, 512, 512, 0, 1024, 102400, false, false>(smem, acc,
            A.g4, A.b4, nullptr, nullptr, tid, lane, wu, wrI, wcI, lg, lc, bidx);
    }
    // P6a: h5(512) -> out cols 0-511, +bo, sigmoid
    {
        f32x4 acc[2][4];
#pragma unroll
        for (int a = 0; a < 2; ++a)
#pragma unroll
            for (int c = 0; c < 4; ++c) acc[a][c] = (f32x4){0.f, 0.f, 0.f, 0.f};
        gemm_h<16, 512, 512, 65536, true, 0, 1024>(smem, A.D3, 0,
            lane, wu, wrI, wcI, lg, lc, fswz, acc);
        out_epi<512, 0>(acc, A.bo, A.out, row0, wrI, wcI, lg, lc);
    }
    // P6b: h5(512) -> out cols 512-783, +bo, sigmoid
    {
        f32x4 acc[2][3];
#pragma unroll
        for (int a = 0; a < 2; ++a)
#pragma unroll
            for (int c = 0; c < 3; ++c) acc[a][c] = (f32x4){0.f, 0.f, 0.f, 0.f};
        gemm_h<16, 384, 512, 65536, true, 0, 1024>(smem, A.D3, 512,
            lane, wu, wrI, wcI, lg, lc, fswz, acc);
        out_epi<384, 512>(acc, A.bo, A.out, row0, wrI, wcI, lg, lc);
    }
}

// ---------------- deterministic reduction of |latent| partials ----------------
__global__ void reduce_abs(const float* __restrict__ partials, float* __restrict__ out) {
    __shared__ float sm[256];
    float s = 0.f;
    for (int i = threadIdx.x; i < 1024; i += 256) s += partials[i];  // fixed order
    sm[threadIdx.x] = s;
    __syncthreads();
    for (int step = 128; step > 0; step >>= 1) {
        if (threadIdx.x < step) sm[threadIdx.x] += sm[threadIdx.x + step];
        __syncthreads();
    }
    if (threadIdx.x == 0) out[0] = sm[0];
}

extern "C" void kernel_launch(void* const* d_in, const int* in_sizes, int n_in,
                              void* d_out, int out_size, void* d_ws, size_t ws_size,
                              hipStream_t stream)
{
    const float* x   = (const float*)d_in[0];
    const float* W1  = (const float*)d_in[1];
    const float* g1  = (const float*)d_in[2];
    const float* b1  = (const float*)d_in[3];
    const float* W2  = (const float*)d_in[4];
    const float* g2  = (const float*)d_in[5];
    const float* b2  = (const float*)d_in[6];
    const float* W3  = (const float*)d_in[7];
    const float* b3  = (const float*)d_in[8];
    const float* gh  = (const float*)d_in[9];
    const float* bh  = (const float*)d_in[10];
    const float* D1  = (const float*)d_in[11];
    const float* g3  = (const float*)d_in[12];
    const float* b3n = (const float*)d_in[13];
    const float* D2  = (const float*)d_in[14];
    const float* g4  = (const float*)d_in[15];
    const float* b4  = (const float*)d_in[16];
    const float* D3  = (const float*)d_in[17];
    const float* bo  = (const float*)d_in[18];

    char* ws = (char*)d_ws;
    size_t off = 0;
    auto alloc = [&](size_t bytes) -> char* {
        char* p = ws + off;
        off += (bytes + 255) & ~(size_t)255;
        return p;
    };
    unsigned short* W1p = (unsigned short*)alloc((size_t)512 * 800 * 2);
    unsigned short* W2p = (unsigned short*)alloc((size_t)384 * 512 * 2);
    unsigned short* W3p = (unsigned short*)alloc((size_t)128 * 288 * 2);
    unsigned short* D1p = (unsigned short*)alloc((size_t)384 * 128 * 2);
    unsigned short* D2p = (unsigned short*)alloc((size_t)512 * 288 * 2);
    unsigned short* D3p = (unsigned short*)alloc((size_t)896 * 512 * 2);
    float* partials = (float*)alloc(1024 * 4);

    CvtArgs ca;
    ca.src[0] = W1; ca.dst[0] = W1p; ca.O[0] = 512; ca.K[0] = 784; ca.KP[0] = 800;
    ca.src[1] = W2; ca.dst[1] = W2p; ca.O[1] = 264; ca.K[1] = 512; ca.KP[1] = 512;
    ca.src[2] = W3; ca.dst[2] = W3p; ca.O[2] = 128; ca.K[2] = 264; ca.KP[2] = 288;
    ca.src[3] = D1; ca.dst[3] = D1p; ca.O[3] = 264; ca.K[3] = 128; ca.KP[3] = 128;
    ca.src[4] = D2; ca.dst[4] = D2p; ca.O[4] = 512; ca.K[4] = 264; ca.KP[4] = 288;
    ca.src[5] = D3; ca.dst[5] = D3p; ca.O[5] = 784; ca.K[5] = 512; ca.KP[5] = 512;
    ca.base[0] = 0;    ca.base[1] = 512;  ca.base[2] = 896;
    ca.base[3] = 1024; ca.base[4] = 1408; ca.base[5] = 1920; ca.base[6] = 2816;
    wpad_kernel<<<2816, 256, 0, stream>>>(ca);

    NetArgs na;
    na.x = x;
    na.W1 = W1p; na.W2 = W2p; na.W3 = W3p; na.D1 = D1p; na.D2 = D2p; na.D3 = D3p;
    na.g1 = g1; na.b1 = b1; na.g2 = g2; na.b2 = b2;
    na.gh = gh; na.bh = bh; na.b3 = b3;
    na.g3 = g3; na.b3n = b3n; na.g4 = g4; na.b4 = b4; na.bo = bo;
    na.out = (float*)d_out;
    na.partials = partials;

    meganet<<<B_ROWS / 64, 1024, 0, stream>>>(na);

    reduce_abs<<<1, 256, 0, stream>>>(partials, (float*)d_out + (size_t)B_ROWS * 784);
}